// Round 1
// baseline (224.036 us; speedup 1.0000x reference)
//
#include <hip/hip_runtime.h>

// out[row] = x[row] - sum(x[row])  for rows of D=512 fp32.
// One wave (64 lanes) per row; 8 floats/lane as 2x float4; shfl butterfly sum.

#define D 512
#define WAVES_PER_BLOCK 4
#define BLOCK (WAVES_PER_BLOCK * 64)

__global__ __launch_bounds__(BLOCK) void rowsub_kernel(const float* __restrict__ x,
                                                       float* __restrict__ out,
                                                       int nrows) {
    const int wave = threadIdx.x >> 6;   // 0..3
    const int lane = threadIdx.x & 63;   // 0..63
    const long long row = (long long)blockIdx.x * WAVES_PER_BLOCK + wave;
    if (row >= nrows) return;

    const float4* __restrict__ xr = reinterpret_cast<const float4*>(x + row * D);
    float4* __restrict__ orow     = reinterpret_cast<float4*>(out + row * D);

    // 512 floats = 128 float4; lanes cover [0,64) and [64,128)
    float4 a = xr[lane];
    float4 b = xr[lane + 64];

    float s = (a.x + a.y) + (a.z + a.w) + (b.x + b.y) + (b.z + b.w);

    // 64-lane butterfly reduction
    #pragma unroll
    for (int off = 32; off > 0; off >>= 1)
        s += __shfl_xor(s, off, 64);

    float4 ra = make_float4(a.x - s, a.y - s, a.z - s, a.w - s);
    float4 rb = make_float4(b.x - s, b.y - s, b.z - s, b.w - s);

    orow[lane]      = ra;
    orow[lane + 64] = rb;
}

extern "C" void kernel_launch(void* const* d_in, const int* in_sizes, int n_in,
                              void* d_out, int out_size, void* d_ws, size_t ws_size,
                              hipStream_t stream) {
    const float* x = (const float*)d_in[0];
    float* out = (float*)d_out;
    const int nrows = in_sizes[0] / D;  // 8*8192 = 65536
    const int grid = (nrows + WAVES_PER_BLOCK - 1) / WAVES_PER_BLOCK;
    rowsub_kernel<<<grid, BLOCK, 0, stream>>>(x, out, nrows);
}

// Round 4
// 217.643 us; speedup vs baseline: 1.0294x; 1.0294x over previous
//
#include <hip/hip_runtime.h>

// out[row] = x[row] - sum(x[row])  for rows of D=512 fp32 (65536 rows).
// One wave (64 lanes) handles TWO consecutive rows: 4 independent 16B
// loads issued up-front (MLP), two interleaved 64-lane shfl_xor butterflies
// (ILP), nontemporal vector loads+stores (pure streaming, no reuse).

#define D 512
#define WAVES_PER_BLOCK 4
#define BLOCK (WAVES_PER_BLOCK * 64)

typedef float v4f __attribute__((ext_vector_type(4)));

__global__ __launch_bounds__(BLOCK) void rowsub2_kernel(const float* __restrict__ x,
                                                        float* __restrict__ out,
                                                        int npairs) {
    const int wave = threadIdx.x >> 6;   // 0..3
    const int lane = threadIdx.x & 63;   // 0..63
    const long long pair = (long long)blockIdx.x * WAVES_PER_BLOCK + wave;
    if (pair >= npairs) return;

    // Two consecutive rows = 1024 contiguous floats = 256 v4f.
    const v4f* __restrict__ xr = reinterpret_cast<const v4f*>(x + pair * (2 * D));
    v4f* __restrict__ orow     = reinterpret_cast<v4f*>(out + pair * (2 * D));

    // Issue all 4 loads before any dependent arithmetic.
    v4f a0 = __builtin_nontemporal_load(&xr[lane]);         // row 0, first half
    v4f a1 = __builtin_nontemporal_load(&xr[lane + 64]);    // row 0, second half
    v4f b0 = __builtin_nontemporal_load(&xr[lane + 128]);   // row 1, first half
    v4f b1 = __builtin_nontemporal_load(&xr[lane + 192]);   // row 1, second half

    float s0 = (a0.x + a0.y) + (a0.z + a0.w) + (a1.x + a1.y) + (a1.z + a1.w);
    float s1 = (b0.x + b0.y) + (b0.z + b0.w) + (b1.x + b1.y) + (b1.z + b1.w);

    // Two independent 64-lane butterflies — interleave for ILP.
    #pragma unroll
    for (int off = 32; off > 0; off >>= 1) {
        s0 += __shfl_xor(s0, off, 64);
        s1 += __shfl_xor(s1, off, 64);
    }

    v4f ra0 = a0 - s0;
    v4f ra1 = a1 - s0;
    v4f rb0 = b0 - s1;
    v4f rb1 = b1 - s1;

    __builtin_nontemporal_store(ra0, &orow[lane]);
    __builtin_nontemporal_store(ra1, &orow[lane + 64]);
    __builtin_nontemporal_store(rb0, &orow[lane + 128]);
    __builtin_nontemporal_store(rb1, &orow[lane + 192]);
}

extern "C" void kernel_launch(void* const* d_in, const int* in_sizes, int n_in,
                              void* d_out, int out_size, void* d_ws, size_t ws_size,
                              hipStream_t stream) {
    const float* x = (const float*)d_in[0];
    float* out = (float*)d_out;
    const int nrows = in_sizes[0] / D;          // 65536
    const int npairs = nrows / 2;               // rows are even (8*8192)
    const int grid = (npairs + WAVES_PER_BLOCK - 1) / WAVES_PER_BLOCK;
    rowsub2_kernel<<<grid, BLOCK, 0, stream>>>(x, out, npairs);
}